// Round 8
// baseline (1324.541 us; speedup 1.0000x reference)
//
#include <hip/hip_runtime.h>
#include <hip/hip_bf16.h>
#include <math.h>

// Problem constants
#define BB 4
#define TT 2048
#define BT 8192          // B*T rows
#define DM 512           // d_model
#define DI 1024          // d_inner
#define NH 8
#define HD 128
#define DS 16
#define CONVD 1056       // DI + 2*DSTATE
#define DPROJ 2088       // 2*DI + 2*DSTATE + NHEADS
#define NL 4
#define CL 128           // scan chunk length
#define NCH 16           // TT / CL
#define NE 131072        // 64 dirbh * 2048 state elems

typedef __hip_bfloat16 bf16;
typedef __attribute__((ext_vector_type(8))) short short8;
typedef __attribute__((ext_vector_type(4))) short short4v;
typedef __attribute__((ext_vector_type(4))) float f32x4;

#define AS_G __attribute__((address_space(1)))
#define AS_L __attribute__((address_space(3)))

static __device__ __forceinline__ float b2f_raw(short v){
  union { unsigned u; float f; } c; c.u = ((unsigned)(unsigned short)v) << 16; return c.f;
}

// block-wide reduce of two values across 256 threads (4 waves)
static __device__ __forceinline__ void red2(float& a, float& b, float* sb){
  #pragma unroll
  for (int o = 32; o; o >>= 1){ a += __shfl_down(a, o); b += __shfl_down(b, o); }
  int w = threadIdx.x >> 6;
  if ((threadIdx.x & 63) == 0){ sb[w] = a; sb[4+w] = b; }
  __syncthreads();
  a = sb[0]+sb[1]+sb[2]+sb[3];
  b = sb[4]+sb[5]+sb[6]+sb[7];
}

// ---------------------------------------------------------------------------
// Dtype sniffing (proven-safe; unchanged).
// ---------------------------------------------------------------------------
__global__ __launch_bounds__(256) void detect_dtype(const void* x, int* flagp){
  __shared__ int cnt;
  if (threadIdx.x == 0) cnt = 0;
  __syncthreads();
  const bf16* p = (const bf16*)x;
  int bad = 0;
  for (int i = threadIdx.x; i < 32768; i += 256){
    float v = __bfloat162float(p[i]);
    if (!isfinite(v) || fabsf(v) > 1e4f) bad++;
  }
  atomicAdd(&cnt, bad);
  __syncthreads();
  if (threadIdx.x == 0) *flagp = (cnt > 100) ? 1 : 0;
}

__global__ __launch_bounds__(256) void convert_in(const void* src, bf16* dst, int n,
                                                  const int* flagp){
  int f = *flagp;
  for (int i = blockIdx.x*256 + threadIdx.x; i < n; i += gridDim.x*256){
    if (f) dst[i] = __float2bfloat16(((const float*)src)[i]);
    else   dst[i] = ((const bf16*)src)[i];
  }
}

// ---------------------------------------------------------------------------
// Generic NT GEMM, 128x128 tile, BK=64, FRAGMENT-ORDERED LDS:
// each 16-row x 32-col sub-tile (1024B) is stored in MFMA fragment order —
// staging lane (quad,l16) fetches A[rb*16+l16][kb*32+quad*8..+7] so the
// fragment ds_read is base + lane*16 (conflict-free; r7's 16-way conflict
// came from the row-major stride-128B layout).
// OP=1 +bias(X[N]).
// OP=3 + dt epilogue: cols >= DPROJ-8 compute softplus/dA -> dadt.
// OP=4 C = srow[row]*(A@W^T) + residual(X[z], aliases C), W pre-scaled.
// ---------------------------------------------------------------------------
template<int OP>
__global__ __launch_bounds__(256,3) void gemm_nt(
    const bf16* __restrict__ A, const bf16* __restrict__ W0, const bf16* __restrict__ W1,
    bf16* C, const bf16* X, const float* __restrict__ srow,
    const bf16* db0, const bf16* db1, const bf16* al0, const bf16* al1,
    float2* __restrict__ dadt,
    int M, int N, int K, int lda, long sA, long sC)
{
  const int z = blockIdx.z;
  const bf16* Az = A + (long)z * sA;
  const bf16* W = z ? W1 : W0;
  const int m0 = blockIdx.x * 128, n0 = blockIdx.y * 128;
  __shared__ __align__(16) bf16 As[128*64];   // 16 sub-tiles x 1024B
  __shared__ __align__(16) bf16 Bs[128*64];
  const int tid  = threadIdx.x;
  const int lane = tid & 63, wv = tid >> 6;
  const int wm = wv >> 1, wn = wv & 1;        // wave -> 64x64 quadrant
  const int quad = lane >> 4, l16 = lane & 15;

  f32x4 acc[4][4];
  #pragma unroll
  for (int i=0;i<4;i++)
    #pragma unroll
    for (int j=0;j<4;j++) acc[i][j] = (f32x4){0.f,0.f,0.f,0.f};

  for (int k0 = 0; k0 < K; k0 += 64){
    __syncthreads();                          // prior round's ds_reads done
    #pragma unroll
    for (int is = 0; is < 4; ++is){
      int s  = wv*4 + is;                     // sub-tile 0..15
      int rb = s >> 1, kb = s & 1;
      int rA = m0 + rb*16 + l16;
      const char* gA = (const char*)(Az + (long)rA*lda + k0 + kb*32 + quad*8);
      char* lA = (char*)As + s*1024;          // wave-uniform base + lane*16
      __builtin_amdgcn_global_load_lds((const AS_G void*)gA, (AS_L void*)lA, 16, 0, 0);
      int rB = n0 + rb*16 + l16; rB = rB < N ? rB : N-1;   // clamp OOB rows
      const char* gB = (const char*)(W + (long)rB*K + k0 + kb*32 + quad*8);
      char* lB = (char*)Bs + s*1024;
      __builtin_amdgcn_global_load_lds((const AS_G void*)gB, (AS_L void*)lB, 16, 0, 0);
    }
    __syncthreads();                          // drains vmcnt before barrier
    #pragma unroll
    for (int sk = 0; sk < 2; ++sk){
      short8 af[4], bfr[4];
      #pragma unroll
      for (int mi=0;mi<4;mi++)
        af[mi]  = *(const short8*)((const char*)As + ((wm*4+mi)*2 + sk)*1024 + lane*16);
      #pragma unroll
      for (int ni=0;ni<4;ni++)
        bfr[ni] = *(const short8*)((const char*)Bs + ((wn*4+ni)*2 + sk)*1024 + lane*16);
      #pragma unroll
      for (int mi=0;mi<4;mi++)
        #pragma unroll
        for (int ni=0;ni<4;ni++)
          acc[mi][ni] = __builtin_amdgcn_mfma_f32_16x16x32_bf16(af[mi], bfr[ni], acc[mi][ni], 0, 0, 0);
    }
  }

  bf16* Cz = C + (long)z * sC;
  const bf16* Xz = (OP==4) ? (X + (long)z * sC) : X;
  const bf16* db = z ? db1 : db0;
  const bf16* al = z ? al1 : al0;
  #pragma unroll
  for (int mi=0;mi<4;mi++){
    #pragma unroll
    for (int ni=0;ni<4;ni++){
      #pragma unroll
      for (int r=0;r<4;r++){
        int row = m0 + wm*64 + mi*16 + quad*4 + r;
        int col = n0 + wn*64 + ni*16 + l16;
        if (col < N){
          float v = acc[mi][ni][r];
          if (OP==1) v += __bfloat162float(X[col]);
          if (OP==4){
            v = v * srow[(long)z*BT + row] + __bfloat162float(Xz[(long)row*N + col]);
          }
          Cz[(long)row*N + col] = __float2bfloat16(v);
          if (OP==3 && col >= DPROJ-8){
            int h = col - (DPROJ-8), b = row >> 11, t = row & 2047;
            float xv = v + __bfloat162float(db[h]);
            float sp = (xv > 20.f) ? xv : log1pf(expf(xv));
            float da = expf(-expf(__bfloat162float(al[h])) * sp);
            float2 dd; dd.x = da; dd.y = sp;
            dadt[((long)(z*BB + b)*NH + h)*TT + t] = dd;
          }
        }
      }
    }
  }
}

// ---------------------------------------------------------------------------
// LayerNorm of embed output (512) -> h_f and time-reversed h_b
// ---------------------------------------------------------------------------
__global__ __launch_bounds__(256) void embed_ln(const bf16* __restrict__ hp,
    const bf16* __restrict__ w, const bf16* __restrict__ bb, bf16* __restrict__ h)
{
  __shared__ float sb[8];
  int bt = blockIdx.x; int b = bt >> 11, t = bt & 2047;
  const bf16* r = hp + (long)bt*DM;
  int c0 = threadIdx.x, c1 = threadIdx.x + 256;
  float v0 = __bfloat162float(r[c0]);
  float v1 = __bfloat162float(r[c1]);
  float s = v0+v1, ss = v0*v0+v1*v1;
  red2(s, ss, sb);
  float m = s / DM;
  float var = ss / DM - m*m;
  float rs = rsqrtf(fmaxf(var, 0.f) + 1e-5f);
  float a0 = (v0-m)*rs*__bfloat162float(w[c0]) + __bfloat162float(bb[c0]);
  float a1 = (v1-m)*rs*__bfloat162float(w[c1]) + __bfloat162float(bb[c1]);
  bf16* o0 = h + (long)bt*DM;
  bf16* o1 = h + ((long)BT + (long)b*TT + (TT-1-t)) * DM;
  o0[c0] = __float2bfloat16(a0); o0[c1] = __float2bfloat16(a1);
  o1[c0] = __float2bfloat16(a0); o1[c1] = __float2bfloat16(a1);
}

// ---------------------------------------------------------------------------
// Causal depthwise conv (K=4) + bias + SiLU — vectorized (round 5)
// ---------------------------------------------------------------------------
__global__ __launch_bounds__(256) void conv_silu(const bf16* __restrict__ zx,
    const bf16* __restrict__ cw0, const bf16* __restrict__ cw1,
    const bf16* __restrict__ cb0, const bf16* __restrict__ cb1,
    bf16* __restrict__ xbc)
{
  int bt = blockIdx.x, dir = blockIdx.y;
  int t = bt & 2047;
  const bf16* cw = dir ? cw1 : cw0;
  const bf16* cb = dir ? cb1 : cb0;
  const bf16* zr = zx + ((long)dir*BT + bt)*DPROJ + DI;  // row t, col 1024
  bf16* orow = xbc + ((long)dir*BT + bt)*CONVD;
  for (int cg = threadIdx.x; cg < CONVD/4; cg += 256){   // 264 groups of 4 ch
    int c = cg*4;
    short8 w01 = *(const short8*)(cw + c*4);       // ch c (j0..3), ch c+1
    short8 w23 = *(const short8*)(cw + c*4 + 8);   // ch c+2, ch c+3
    short4v bi = *(const short4v*)(cb + c);
    float acc[4];
    #pragma unroll
    for (int k=0;k<4;k++) acc[k] = b2f_raw(bi[k]);
    #pragma unroll
    for (int j=0;j<4;j++){
      if (t - 3 + j >= 0){
        short4v xv = *(const short4v*)(zr + (long)(j-3)*DPROJ + c);
        acc[0] = fmaf(b2f_raw(w01[j]),   b2f_raw(xv[0]), acc[0]);
        acc[1] = fmaf(b2f_raw(w01[4+j]), b2f_raw(xv[1]), acc[1]);
        acc[2] = fmaf(b2f_raw(w23[j]),   b2f_raw(xv[2]), acc[2]);
        acc[3] = fmaf(b2f_raw(w23[4+j]), b2f_raw(xv[3]), acc[3]);
      }
    }
    short4v ov;
    #pragma unroll
    for (int k=0;k<4;k++){
      float sg = 1.f / (1.f + expf(-acc[k]));
      ov[k] = (short)__bfloat16_as_ushort(__float2bfloat16(acc[k] * sg));
    }
    *(short4v*)(orow + c) = ov;
  }
}

// ---------------------------------------------------------------------------
// Chunked selective scan (SSD), p-split: one wave per (chunk, dbh, p-half),
// lane owns ONE p x all 16 n -> 2048 waves = 8 waves/CU (2x r7's hiding).
// ---------------------------------------------------------------------------
__global__ __launch_bounds__(256,1) void chunk_local(const bf16* __restrict__ xbc,
    const float2* __restrict__ dadt, float* __restrict__ SC, float* __restrict__ Pc)
{
  int c = blockIdx.x;
  int wv = threadIdx.x >> 6, lane = threadIdx.x & 63;
  int dbh = blockIdx.y*2 + (wv >> 1);
  int ph  = wv & 1;
  int dir = dbh >> 5, b = (dbh >> 3) & 3, h = dbh & 7;
  const bf16* xr = xbc + ((long)dir*BT + (long)b*TT)*CONVD;
  const float2* ddr = dadt + (long)dbh*TT;
  const int xoff = h*HD + ph*64 + lane;
  float s[16];
  #pragma unroll
  for (int n=0;n<16;n++) s[n] = 0.f;
  float pacc = 1.f;
  const int c0 = c*CL;

  float  gx[2][4];
  short8 gB0[2][4], gB1[2][4];
  float2 gd[2][4];

  auto LOADG = [&](int buf, int t0){
    #pragma unroll
    for (int i=0;i<4;i++){
      const bf16* rr = xr + (long)(t0+i)*CONVD;
      gx[buf][i]  = __bfloat162float(rr[xoff]);
      gB0[buf][i] = *(const short8*)(rr + DI);
      gB1[buf][i] = *(const short8*)(rr + DI + 8);
      gd[buf][i]  = ddr[t0+i];
    }
  };
  auto STEPG = [&](int buf){
    #pragma unroll
    for (int i=0;i<4;i++){
      float da = gd[buf][i].x, dt = gd[buf][i].y;
      float xd = gx[buf][i]*dt;
      #pragma unroll
      for (int n=0;n<8;n++){
        s[n]   = fmaf(da, s[n],   xd*b2f_raw(gB0[buf][i][n]));
        s[8+n] = fmaf(da, s[8+n], xd*b2f_raw(gB1[buf][i][n]));
      }
      pacc *= da;
    }
  };

  LOADG(0, c0);
  for (int t0 = c0; t0 < c0+CL; t0 += 8){
    LOADG(1, t0+4);
    STEPG(0);
    if (t0+8 < c0+CL) LOADG(0, t0+8);
    STEPG(1);
  }
  float* sc = SC + (long)c*NE + (long)dbh*2048 + ph*1024 + lane*16;
  #pragma unroll
  for (int n=0;n<16;n++) sc[n] = s[n];
  if (ph == 0 && lane == 0) Pc[dbh*NCH + c] = pacc;
}

__global__ __launch_bounds__(256) void chunk_combine(float* __restrict__ SC,
    const float* __restrict__ Pc)
{
  int e = blockIdx.x*256 + threadIdx.x;   // 131072 total
  int dbh = e >> 11;
  float s = 0.f;
  #pragma unroll
  for (int c=0;c<NCH;c++){
    float tmp = SC[(long)c*NE + e];
    SC[(long)c*NE + e] = s;               // exclusive scan in place -> S_init
    s = Pc[dbh*NCH + c]*s + tmp;
  }
}

// chunk_apply: rescan seeded with S_init; fused gate g = y*silu(z) in fp32,
// written in-place into zx's z-cols. NO in-kernel reduction (row_scale does
// the sum(g^2) pass — r7's per-t shfl chain was the 84us latency bomb).
__global__ __launch_bounds__(256,1) void chunk_apply(const bf16* __restrict__ xbc,
    bf16* zx, const float2* __restrict__ dadt, const float* __restrict__ SC,
    const bf16* __restrict__ D0, const bf16* __restrict__ D1)
{
  int c = blockIdx.x;
  int wv = threadIdx.x >> 6, lane = threadIdx.x & 63;
  int dbh = blockIdx.y*2 + (wv >> 1);
  int ph  = wv & 1;
  int dir = dbh >> 5, b = (dbh >> 3) & 3, h = dbh & 7;
  const bf16* xr = xbc + ((long)dir*BT + (long)b*TT)*CONVD;
  bf16* zrow = zx + ((long)dir*BT + (long)b*TT)*DPROJ;
  const float2* ddr = dadt + (long)dbh*TT;
  const int xoff = h*HD + ph*64 + lane;
  float Dv = __bfloat162float(dir ? D1[h] : D0[h]);
  const float* sc = SC + (long)c*NE + (long)dbh*2048 + ph*1024 + lane*16;
  float s[16];
  #pragma unroll
  for (int n=0;n<16;n++) s[n] = sc[n];
  const int c0 = c*CL;

  float  gx[2][4], gz[2][4];
  short8 gB0[2][4], gB1[2][4], gC0[2][4], gC1[2][4];
  float2 gd[2][4];

  auto LOADG = [&](int buf, int t0){
    #pragma unroll
    for (int i=0;i<4;i++){
      const bf16* rr = xr + (long)(t0+i)*CONVD;
      gx[buf][i]  = __bfloat162float(rr[xoff]);
      gB0[buf][i] = *(const short8*)(rr + DI);
      gB1[buf][i] = *(const short8*)(rr + DI + 8);
      gC0[buf][i] = *(const short8*)(rr + DI + DS);
      gC1[buf][i] = *(const short8*)(rr + DI + DS + 8);
      gz[buf][i]  = __bfloat162float(zrow[(long)(t0+i)*DPROJ + xoff]);
      gd[buf][i]  = ddr[t0+i];
    }
  };
  auto STEPG = [&](int buf, int t0){
    #pragma unroll
    for (int i=0;i<4;i++){
      float da = gd[buf][i].x, dt = gd[buf][i].y;
      float xd = gx[buf][i]*dt;
      float a = 0.f;
      #pragma unroll
      for (int n=0;n<8;n++){
        s[n]   = fmaf(da, s[n],   xd*b2f_raw(gB0[buf][i][n]));
        a      = fmaf(s[n],   b2f_raw(gC0[buf][i][n]), a);
        s[8+n] = fmaf(da, s[8+n], xd*b2f_raw(gB1[buf][i][n]));
        a      = fmaf(s[8+n], b2f_raw(gC1[buf][i][n]), a);
      }
      float y = a + Dv*gx[buf][i];
      float zv = gz[buf][i];
      float g = y * zv / (1.f + expf(-zv));
      zrow[(long)(t0+i)*DPROJ + xoff] = __float2bfloat16(g);
    }
  };

  LOADG(0, c0);
  for (int t0 = c0; t0 < c0+CL; t0 += 8){
    LOADG(1, t0+4);
    STEPG(0, t0);
    if (t0+8 < c0+CL) LOADG(0, t0+8);
    STEPG(1, t0+4);
  }
}

// ---------------------------------------------------------------------------
// srow[row] = rsqrt(mean_DI(g^2)+eps); one wave per row of zx's g-cols.
// ---------------------------------------------------------------------------
__global__ __launch_bounds__(256) void row_scale(const bf16* __restrict__ zx,
    float* __restrict__ srow)
{
  int row = blockIdx.x*4 + (threadIdx.x >> 6);   // 0..16383
  int lane = threadIdx.x & 63;
  const bf16* g = zx + (long)row*DPROJ + lane*16;
  short8 a = *(const short8*)g;
  short8 b = *(const short8*)(g + 8);
  float ss = 0.f;
  #pragma unroll
  for (int k=0;k<8;k++){
    float va = b2f_raw(a[k]), vb = b2f_raw(b[k]);
    ss += va*va + vb*vb;
  }
  #pragma unroll
  for (int o=1;o<64;o<<=1) ss += __shfl_xor(ss, o);
  if (lane == 0) srow[row] = rsqrtf(ss / DI + 1e-5f);
}

// ---------------------------------------------------------------------------
// wg[z][o][i] = out_w[z][o][i] * rms_w[z][i]  (row-scale commutation)
// ---------------------------------------------------------------------------
__global__ __launch_bounds__(256) void wg_scale(const bf16* __restrict__ w0,
    const bf16* __restrict__ w1, const bf16* __restrict__ r0,
    const bf16* __restrict__ r1, bf16* __restrict__ wg)
{
  int i = blockIdx.x*256 + threadIdx.x;   // 0..2*DM*DI-1
  int z = i >= DM*DI; int rem = z ? i - DM*DI : i;
  int col = rem & (DI-1);
  const bf16* w = z ? w1 : w0; const bf16* r = z ? r1 : r0;
  wg[i] = __float2bfloat16(__bfloat162float(w[rem]) * __bfloat162float(r[col]));
}

// ---------------------------------------------------------------------------
// Final LN over concat(h_f[b,t], h_b[b,T-1-t]) (1024) -> d_out
// ---------------------------------------------------------------------------
__global__ __launch_bounds__(256) void final_ln(const bf16* __restrict__ h,
    const bf16* __restrict__ lw, const bf16* __restrict__ lb, void* out,
    int mode, const int* flagp)
{
  __shared__ float sb[8];
  int bt = blockIdx.x; int b = bt >> 11, t = bt & 2047;
  int f32out = mode ? *flagp : 0;
  const bf16* rf = h + (long)bt*DM;
  const bf16* rb = h + ((long)BT + (long)b*TT + (TT-1-t))*DM;
  float v[4], s = 0.f, ss = 0.f;
  #pragma unroll
  for (int i=0;i<4;i++){
    int c = threadIdx.x + i*256;
    v[i] = __bfloat162float(c < DM ? rf[c] : rb[c-DM]);
    s += v[i]; ss += v[i]*v[i];
  }
  red2(s, ss, sb);
  float m = s / (2*DM);
  float var = ss / (2*DM) - m*m;
  float rs = rsqrtf(fmaxf(var, 0.f) + 1e-5f);
  #pragma unroll
  for (int i=0;i<4;i++){
    int c = threadIdx.x + i*256;
    float o = (v[i]-m)*rs*__bfloat162float(lw[c]) + __bfloat162float(lb[c]);
    if (f32out) ((float*)out)[(long)bt*(2*DM) + c] = o;
    else        ((bf16*)out)[(long)bt*(2*DM) + c] = __float2bfloat16(o);
  }
}

// ---------------------------------------------------------------------------
extern "C" void kernel_launch(void* const* d_in, const int* in_sizes, int n_in,
                              void* d_out, int out_size, void* d_ws, size_t ws_size,
                              hipStream_t stream)
{
  char* wsp = (char*)d_ws;
  auto take = [&](size_t bytes){ char* p = wsp; wsp += (bytes + 63) & ~(size_t)63; return p; };
  int*   flagp = (int*)  take(4);
  bf16*  h     = (bf16*) take((size_t)2*BT*DM*2);      // 16.78 MB
  bf16*  zx    = (bf16*) take((size_t)2*BT*DPROJ*2);   // 68.42 MB (gated in place)
  bf16*  xbc   = (bf16*) take((size_t)2*BT*CONVD*2);   // 34.60 MB
  float2* dadt = (float2*)take((size_t)2*BB*NH*TT*8);  // 1.05 MB
  float* srowb = (float*)take((size_t)2*BT*4);         // 64 KB
  float* Pc    = (float*)take((size_t)64*NCH*4);       // 4 KB
  float* SC    = (float*)take((size_t)NCH*NE*4);       // 8.39 MB chunk states
  bf16*  wg    = (bf16*)SC;   // overlays SC: live only after chunk_apply
  size_t needDirect = (size_t)(wsp - (char*)d_ws);     // ~129.3 MB (proven safe)

  static const int cnt[23] = {
    BT*256, DM*256, DM, DM, DM, 2*DM, 2*DM,
    NL*DPROJ*DM, NL*CONVD*4, NL*CONVD, NL*NH, NL*NH, NL*NH, NL*DI, NL*DM*DI,
    NL*DPROJ*DM, NL*CONVD*4, NL*CONVD, NL*NH, NL*NH, NL*NH, NL*DI, NL*DM*DI };
  bf16* canon[23];
  for (int i = 0; i < 23; ++i) canon[i] = (bf16*)take((size_t)cnt[i]*2);
  size_t needFull = (size_t)(wsp - (char*)d_ws);

  const int convMode = (ws_size >= needFull) ? 1 : 0;

  const bf16* in[23];
  if (convMode){
    detect_dtype<<<1,256,0,stream>>>(d_in[0], flagp);
    for (int i = 0; i < 23; ++i){
      int grid = (cnt[i] + 255)/256; if (grid > 2048) grid = 2048;
      convert_in<<<grid,256,0,stream>>>(d_in[i], canon[i], cnt[i], flagp);
      in[i] = canon[i];
    }
  } else {
    for (int i = 0; i < 23; ++i) in[i] = (const bf16*)d_in[i];
  }

  const bf16* x       = in[0];
  const bf16* embed_w = in[1];
  const bf16* embed_b = in[2];
  const bf16* ln1_w   = in[3];
  const bf16* ln1_b   = in[4];
  const bf16* lnout_w = in[5];
  const bf16* lnout_b = in[6];
  const bf16* in_w[2]   = {in[7],  in[15]};
  const bf16* conv_w[2] = {in[8],  in[16]};
  const bf16* conv_b[2] = {in[9],  in[17]};
  const bf16* dt_b[2]   = {in[10], in[18]};
  const bf16* A_log[2]  = {in[11], in[19]};
  const bf16* Dp[2]     = {in[12], in[20]};
  const bf16* rms_w[2]  = {in[13], in[21]};
  const bf16* out_w[2]  = {in[14], in[22]};

  bf16* hpre = xbc;   // embed output parks in xbc (free until layer-0 conv)

  gemm_nt<1><<<dim3(64,4,1),256,0,stream>>>(x, embed_w, embed_w, hpre, embed_b,
      nullptr, nullptr, nullptr, nullptr, nullptr, nullptr,
      BT, DM, 256, 256, 0, 0);
  embed_ln<<<dim3(BT),256,0,stream>>>(hpre, ln1_w, ln1_b, h);

  for (int i = 0; i < NL; ++i){
    gemm_nt<3><<<dim3(64,17,2),256,0,stream>>>(h,
        in_w[0]+(size_t)i*DPROJ*DM, in_w[1]+(size_t)i*DPROJ*DM,
        zx, nullptr, nullptr,
        dt_b[0]+i*NH, dt_b[1]+i*NH, A_log[0]+i*NH, A_log[1]+i*NH, dadt,
        BT, DPROJ, DM, DM, (long)BT*DM, (long)BT*DPROJ);
    conv_silu<<<dim3(BT,2),256,0,stream>>>(zx,
        conv_w[0]+(size_t)i*CONVD*4, conv_w[1]+(size_t)i*CONVD*4,
        conv_b[0]+(size_t)i*CONVD, conv_b[1]+(size_t)i*CONVD, xbc);
    chunk_local<<<dim3(NCH,32),256,0,stream>>>(xbc, dadt, SC, Pc);
    chunk_combine<<<dim3(NE/256),256,0,stream>>>(SC, Pc);
    chunk_apply<<<dim3(NCH,32),256,0,stream>>>(xbc, zx, dadt, SC,
        Dp[0]+i*NH, Dp[1]+i*NH);
    row_scale<<<dim3(2*BT/4),256,0,stream>>>(zx, srowb);
    wg_scale<<<dim3(2*DM*DI/256),256,0,stream>>>(out_w[0]+(size_t)i*DM*DI,
        out_w[1]+(size_t)i*DM*DI, rms_w[0]+(size_t)i*DI, rms_w[1]+(size_t)i*DI, wg);
    gemm_nt<4><<<dim3(64,4,2),256,0,stream>>>(zx, wg, wg+(size_t)DM*DI,
        h, h, srowb, nullptr, nullptr, nullptr, nullptr, nullptr,
        BT, DM, DI, DPROJ, (long)BT*DPROJ, (long)BT*DM);
  }

  final_ln<<<dim3(BT),256,0,stream>>>(h, lnout_w, lnout_b, d_out, convMode, flagp);
  (void)needDirect; (void)in_sizes; (void)n_in; (void)out_size;
}

// Round 9
// 1272.997 us; speedup vs baseline: 1.0405x; 1.0405x over previous
//
#include <hip/hip_runtime.h>
#include <hip/hip_bf16.h>
#include <math.h>

// Problem constants
#define BB 4
#define TT 2048
#define BT 8192          // B*T rows
#define DM 512           // d_model
#define DI 1024          // d_inner
#define NH 8
#define HD 128
#define DS 16
#define CONVD 1056       // DI + 2*DSTATE
#define DPROJ 2088       // 2*DI + 2*DSTATE + NHEADS
#define NL 4
#define CL 128           // scan chunk length
#define NCH 16           // TT / CL
#define NE 131072        // 64 dirbh * 2048 state elems

typedef __hip_bfloat16 bf16;
typedef __attribute__((ext_vector_type(8))) short short8;
typedef __attribute__((ext_vector_type(4))) short short4v;
typedef __attribute__((ext_vector_type(4))) float f32x4;

#define AS_G __attribute__((address_space(1)))
#define AS_L __attribute__((address_space(3)))

static __device__ __forceinline__ float b2f_raw(short v){
  union { unsigned u; float f; } c; c.u = ((unsigned)(unsigned short)v) << 16; return c.f;
}

// block-wide reduce of two values across 256 threads (4 waves)
static __device__ __forceinline__ void red2(float& a, float& b, float* sb){
  #pragma unroll
  for (int o = 32; o; o >>= 1){ a += __shfl_down(a, o); b += __shfl_down(b, o); }
  int w = threadIdx.x >> 6;
  if ((threadIdx.x & 63) == 0){ sb[w] = a; sb[4+w] = b; }
  __syncthreads();
  a = sb[0]+sb[1]+sb[2]+sb[3];
  b = sb[4]+sb[5]+sb[6]+sb[7];
}

// ---------------------------------------------------------------------------
// Dtype sniffing (proven-safe; unchanged).
// ---------------------------------------------------------------------------
__global__ __launch_bounds__(256) void detect_dtype(const void* x, int* flagp){
  __shared__ int cnt;
  if (threadIdx.x == 0) cnt = 0;
  __syncthreads();
  const bf16* p = (const bf16*)x;
  int bad = 0;
  for (int i = threadIdx.x; i < 32768; i += 256){
    float v = __bfloat162float(p[i]);
    if (!isfinite(v) || fabsf(v) > 1e4f) bad++;
  }
  atomicAdd(&cnt, bad);
  __syncthreads();
  if (threadIdx.x == 0) *flagp = (cnt > 100) ? 1 : 0;
}

__global__ __launch_bounds__(256) void convert_in(const void* src, bf16* dst, int n,
                                                  const int* flagp){
  int f = *flagp;
  for (int i = blockIdx.x*256 + threadIdx.x; i < n; i += gridDim.x*256){
    if (f) dst[i] = __float2bfloat16(((const float*)src)[i]);
    else   dst[i] = ((const bf16*)src)[i];
  }
}

// ---------------------------------------------------------------------------
// Generic NT GEMM — EXACT round-5 K-loop (fastest measured: 69us, 4.4M LDS
// conflicts and all; r6/r7/r8 BK/layout variants all regressed — the kernel
// is LLC-bandwidth/latency bound on tile re-reads, not LDS-bound).
// 128x128 tile, BK=32, row-major 64B LDS rows, async 16B staging.
// OP=1 +bias(X[N]).
// OP=3 + dt epilogue: cols >= DPROJ-8 compute softplus/dA -> dadt.
// OP=4 C = srow[row]*(A@W^T) + residual(X[z], aliases C), W pre-scaled.
// ---------------------------------------------------------------------------
template<int OP>
__global__ __launch_bounds__(256) void gemm_nt(
    const bf16* __restrict__ A, const bf16* __restrict__ W0, const bf16* __restrict__ W1,
    bf16* C, const bf16* X, const float* __restrict__ srow,
    const bf16* db0, const bf16* db1, const bf16* al0, const bf16* al1,
    float2* __restrict__ dadt,
    int M, int N, int K, int lda, long sA, long sC)
{
  const int z = blockIdx.z;
  const bf16* Az = A + (long)z * sA;
  const bf16* W = z ? W1 : W0;
  const int m0 = blockIdx.x * 128, n0 = blockIdx.y * 128;
  __shared__ __align__(16) bf16 As[128*32];
  __shared__ __align__(16) bf16 Bs[128*32];
  const int tid  = threadIdx.x;
  const int lane = tid & 63, wv = tid >> 6;
  const int wm = wv >> 1, wn = wv & 1;          // wave -> 64x64 quadrant
  const int quad = lane >> 4, l16 = lane & 15;
  const int srow_ = lane >> 2;                  // staging row within 16-row chunk
  const int skb   = (lane & 3) * 16;            // staging byte offset in 64B row

  f32x4 acc[4][4];
  #pragma unroll
  for (int i=0;i<4;i++)
    #pragma unroll
    for (int j=0;j<4;j++) acc[i][j] = (f32x4){0.f,0.f,0.f,0.f};

  for (int k0 = 0; k0 < K; k0 += 32){
    __syncthreads();                            // prior iter's ds_reads done
    #pragma unroll
    for (int is = 0; is < 2; ++is){
      int r = is*64 + wv*16 + srow_;            // 0..127 tile row
      const char* gA = (const char*)(Az + (long)(m0 + r)*lda + k0) + skb;
      char* lA = (char*)As + (long)(is*64 + wv*16)*64;
      __builtin_amdgcn_global_load_lds((const AS_G void*)gA, (AS_L void*)lA, 16, 0, 0);
      int rn = n0 + r; rn = rn < N ? rn : N-1;  // clamp OOB weight rows
      const char* gB = (const char*)(W + (long)rn*K + k0) + skb;
      char* lB = (char*)Bs + (long)(is*64 + wv*16)*64;
      __builtin_amdgcn_global_load_lds((const AS_G void*)gB, (AS_L void*)lB, 16, 0, 0);
    }
    __syncthreads();                            // drains vmcnt before barrier
    short8 af[4], bfr[4];
    #pragma unroll
    for (int mi=0;mi<4;mi++) af[mi]  = *(const short8*)((const char*)As + (long)(wm*64+mi*16+l16)*64 + quad*16);
    #pragma unroll
    for (int ni=0;ni<4;ni++) bfr[ni] = *(const short8*)((const char*)Bs + (long)(wn*64+ni*16+l16)*64 + quad*16);
    #pragma unroll
    for (int mi=0;mi<4;mi++)
      #pragma unroll
      for (int ni=0;ni<4;ni++)
        acc[mi][ni] = __builtin_amdgcn_mfma_f32_16x16x32_bf16(af[mi], bfr[ni], acc[mi][ni], 0, 0, 0);
  }

  bf16* Cz = C + (long)z * sC;
  const bf16* Xz = (OP==4) ? (X + (long)z * sC) : X;
  const bf16* db = z ? db1 : db0;
  const bf16* al = z ? al1 : al0;
  #pragma unroll
  for (int mi=0;mi<4;mi++){
    #pragma unroll
    for (int ni=0;ni<4;ni++){
      #pragma unroll
      for (int r=0;r<4;r++){
        int row = m0 + wm*64 + mi*16 + quad*4 + r;
        int col = n0 + wn*64 + ni*16 + l16;
        if (col < N){
          float v = acc[mi][ni][r];
          if (OP==1) v += __bfloat162float(X[col]);
          if (OP==4){
            v = v * srow[(long)z*BT + row] + __bfloat162float(Xz[(long)row*N + col]);
          }
          Cz[(long)row*N + col] = __float2bfloat16(v);
          if (OP==3 && col >= DPROJ-8){
            int h = col - (DPROJ-8), b = row >> 11, t = row & 2047;
            float xv = v + __bfloat162float(db[h]);
            float sp = (xv > 20.f) ? xv : log1pf(expf(xv));
            float da = expf(-expf(__bfloat162float(al[h])) * sp);
            float2 dd; dd.x = da; dd.y = sp;
            dadt[((long)(z*BB + b)*NH + h)*TT + t] = dd;
          }
        }
      }
    }
  }
}

// ---------------------------------------------------------------------------
// LayerNorm of embed output (512) -> h_f and time-reversed h_b
// ---------------------------------------------------------------------------
__global__ __launch_bounds__(256) void embed_ln(const bf16* __restrict__ hp,
    const bf16* __restrict__ w, const bf16* __restrict__ bb, bf16* __restrict__ h)
{
  __shared__ float sb[8];
  int bt = blockIdx.x; int b = bt >> 11, t = bt & 2047;
  const bf16* r = hp + (long)bt*DM;
  int c0 = threadIdx.x, c1 = threadIdx.x + 256;
  float v0 = __bfloat162float(r[c0]);
  float v1 = __bfloat162float(r[c1]);
  float s = v0+v1, ss = v0*v0+v1*v1;
  red2(s, ss, sb);
  float m = s / DM;
  float var = ss / DM - m*m;
  float rs = rsqrtf(fmaxf(var, 0.f) + 1e-5f);
  float a0 = (v0-m)*rs*__bfloat162float(w[c0]) + __bfloat162float(bb[c0]);
  float a1 = (v1-m)*rs*__bfloat162float(w[c1]) + __bfloat162float(bb[c1]);
  bf16* o0 = h + (long)bt*DM;
  bf16* o1 = h + ((long)BT + (long)b*TT + (TT-1-t)) * DM;
  o0[c0] = __float2bfloat16(a0); o0[c1] = __float2bfloat16(a1);
  o1[c0] = __float2bfloat16(a0); o1[c1] = __float2bfloat16(a1);
}

// ---------------------------------------------------------------------------
// Causal depthwise conv (K=4) + bias + SiLU — vectorized (round 5)
// ---------------------------------------------------------------------------
__global__ __launch_bounds__(256) void conv_silu(const bf16* __restrict__ zx,
    const bf16* __restrict__ cw0, const bf16* __restrict__ cw1,
    const bf16* __restrict__ cb0, const bf16* __restrict__ cb1,
    bf16* __restrict__ xbc)
{
  int bt = blockIdx.x, dir = blockIdx.y;
  int t = bt & 2047;
  const bf16* cw = dir ? cw1 : cw0;
  const bf16* cb = dir ? cb1 : cb0;
  const bf16* zr = zx + ((long)dir*BT + bt)*DPROJ + DI;  // row t, col 1024
  bf16* orow = xbc + ((long)dir*BT + bt)*CONVD;
  for (int cg = threadIdx.x; cg < CONVD/4; cg += 256){   // 264 groups of 4 ch
    int c = cg*4;
    short8 w01 = *(const short8*)(cw + c*4);       // ch c (j0..3), ch c+1
    short8 w23 = *(const short8*)(cw + c*4 + 8);   // ch c+2, ch c+3
    short4v bi = *(const short4v*)(cb + c);
    float acc[4];
    #pragma unroll
    for (int k=0;k<4;k++) acc[k] = b2f_raw(bi[k]);
    #pragma unroll
    for (int j=0;j<4;j++){
      if (t - 3 + j >= 0){
        short4v xv = *(const short4v*)(zr + (long)(j-3)*DPROJ + c);
        acc[0] = fmaf(b2f_raw(w01[j]),   b2f_raw(xv[0]), acc[0]);
        acc[1] = fmaf(b2f_raw(w01[4+j]), b2f_raw(xv[1]), acc[1]);
        acc[2] = fmaf(b2f_raw(w23[j]),   b2f_raw(xv[2]), acc[2]);
        acc[3] = fmaf(b2f_raw(w23[4+j]), b2f_raw(xv[3]), acc[3]);
      }
    }
    short4v ov;
    #pragma unroll
    for (int k=0;k<4;k++){
      float sg = 1.f / (1.f + expf(-acc[k]));
      ov[k] = (short)__bfloat16_as_ushort(__float2bfloat16(acc[k] * sg));
    }
    *(short4v*)(orow + c) = ov;
  }
}

// ---------------------------------------------------------------------------
// Chunked selective scan (SSD), p-split: one wave per (chunk, dbh, p-half),
// lane owns ONE p x all 16 n -> 2048 waves = 8 waves/CU.
// ---------------------------------------------------------------------------
__global__ __launch_bounds__(256,1) void chunk_local(const bf16* __restrict__ xbc,
    const float2* __restrict__ dadt, float* __restrict__ SC, float* __restrict__ Pc)
{
  int c = blockIdx.x;
  int wv = threadIdx.x >> 6, lane = threadIdx.x & 63;
  int dbh = blockIdx.y*2 + (wv >> 1);
  int ph  = wv & 1;
  int dir = dbh >> 5, b = (dbh >> 3) & 3, h = dbh & 7;
  const bf16* xr = xbc + ((long)dir*BT + (long)b*TT)*CONVD;
  const float2* ddr = dadt + (long)dbh*TT;
  const int xoff = h*HD + ph*64 + lane;
  float s[16];
  #pragma unroll
  for (int n=0;n<16;n++) s[n] = 0.f;
  float pacc = 1.f;
  const int c0 = c*CL;

  float  gx[2][4];
  short8 gB0[2][4], gB1[2][4];
  float2 gd[2][4];

  auto LOADG = [&](int buf, int t0){
    #pragma unroll
    for (int i=0;i<4;i++){
      const bf16* rr = xr + (long)(t0+i)*CONVD;
      gx[buf][i]  = __bfloat162float(rr[xoff]);
      gB0[buf][i] = *(const short8*)(rr + DI);
      gB1[buf][i] = *(const short8*)(rr + DI + 8);
      gd[buf][i]  = ddr[t0+i];
    }
  };
  auto STEPG = [&](int buf){
    #pragma unroll
    for (int i=0;i<4;i++){
      float da = gd[buf][i].x, dt = gd[buf][i].y;
      float xd = gx[buf][i]*dt;
      #pragma unroll
      for (int n=0;n<8;n++){
        s[n]   = fmaf(da, s[n],   xd*b2f_raw(gB0[buf][i][n]));
        s[8+n] = fmaf(da, s[8+n], xd*b2f_raw(gB1[buf][i][n]));
      }
      pacc *= da;
    }
  };

  LOADG(0, c0);
  for (int t0 = c0; t0 < c0+CL; t0 += 8){
    LOADG(1, t0+4);
    STEPG(0);
    if (t0+8 < c0+CL) LOADG(0, t0+8);
    STEPG(1);
  }
  float* sc = SC + (long)c*NE + (long)dbh*2048 + ph*1024 + lane*16;
  #pragma unroll
  for (int n=0;n<16;n++) sc[n] = s[n];
  if (ph == 0 && lane == 0) Pc[dbh*NCH + c] = pacc;
}

__global__ __launch_bounds__(256) void chunk_combine(float* __restrict__ SC,
    const float* __restrict__ Pc)
{
  int e = blockIdx.x*256 + threadIdx.x;   // 131072 total
  int dbh = e >> 11;
  float s = 0.f;
  #pragma unroll
  for (int c=0;c<NCH;c++){
    float tmp = SC[(long)c*NE + e];
    SC[(long)c*NE + e] = s;               // exclusive scan in place -> S_init
    s = Pc[dbh*NCH + c]*s + tmp;
  }
}

// chunk_apply: rescan seeded with S_init; fused gate g = y*silu(z) in fp32,
// written in-place into zx's z-cols. No in-kernel reduction.
__global__ __launch_bounds__(256,1) void chunk_apply(const bf16* __restrict__ xbc,
    bf16* zx, const float2* __restrict__ dadt, const float* __restrict__ SC,
    const bf16* __restrict__ D0, const bf16* __restrict__ D1)
{
  int c = blockIdx.x;
  int wv = threadIdx.x >> 6, lane = threadIdx.x & 63;
  int dbh = blockIdx.y*2 + (wv >> 1);
  int ph  = wv & 1;
  int dir = dbh >> 5, b = (dbh >> 3) & 3, h = dbh & 7;
  const bf16* xr = xbc + ((long)dir*BT + (long)b*TT)*CONVD;
  bf16* zrow = zx + ((long)dir*BT + (long)b*TT)*DPROJ;
  const float2* ddr = dadt + (long)dbh*TT;
  const int xoff = h*HD + ph*64 + lane;
  float Dv = __bfloat162float(dir ? D1[h] : D0[h]);
  const float* sc = SC + (long)c*NE + (long)dbh*2048 + ph*1024 + lane*16;
  float s[16];
  #pragma unroll
  for (int n=0;n<16;n++) s[n] = sc[n];
  const int c0 = c*CL;

  float  gx[2][4], gz[2][4];
  short8 gB0[2][4], gB1[2][4], gC0[2][4], gC1[2][4];
  float2 gd[2][4];

  auto LOADG = [&](int buf, int t0){
    #pragma unroll
    for (int i=0;i<4;i++){
      const bf16* rr = xr + (long)(t0+i)*CONVD;
      gx[buf][i]  = __bfloat162float(rr[xoff]);
      gB0[buf][i] = *(const short8*)(rr + DI);
      gB1[buf][i] = *(const short8*)(rr + DI + 8);
      gC0[buf][i] = *(const short8*)(rr + DI + DS);
      gC1[buf][i] = *(const short8*)(rr + DI + DS + 8);
      gz[buf][i]  = __bfloat162float(zrow[(long)(t0+i)*DPROJ + xoff]);
      gd[buf][i]  = ddr[t0+i];
    }
  };
  auto STEPG = [&](int buf, int t0){
    #pragma unroll
    for (int i=0;i<4;i++){
      float da = gd[buf][i].x, dt = gd[buf][i].y;
      float xd = gx[buf][i]*dt;
      float a = 0.f;
      #pragma unroll
      for (int n=0;n<8;n++){
        s[n]   = fmaf(da, s[n],   xd*b2f_raw(gB0[buf][i][n]));
        a      = fmaf(s[n],   b2f_raw(gC0[buf][i][n]), a);
        s[8+n] = fmaf(da, s[8+n], xd*b2f_raw(gB1[buf][i][n]));
        a      = fmaf(s[8+n], b2f_raw(gC1[buf][i][n]), a);
      }
      float y = a + Dv*gx[buf][i];
      float zv = gz[buf][i];
      float g = y * zv / (1.f + expf(-zv));
      zrow[(long)(t0+i)*DPROJ + xoff] = __float2bfloat16(g);
    }
  };

  LOADG(0, c0);
  for (int t0 = c0; t0 < c0+CL; t0 += 8){
    LOADG(1, t0+4);
    STEPG(0, t0);
    if (t0+8 < c0+CL) LOADG(0, t0+8);
    STEPG(1, t0+4);
  }
}

// ---------------------------------------------------------------------------
// srow[row] = rsqrt(mean_DI(g^2)+eps); one wave per row of zx's g-cols.
// ---------------------------------------------------------------------------
__global__ __launch_bounds__(256) void row_scale(const bf16* __restrict__ zx,
    float* __restrict__ srow)
{
  int row = blockIdx.x*4 + (threadIdx.x >> 6);   // 0..16383
  int lane = threadIdx.x & 63;
  const bf16* g = zx + (long)row*DPROJ + lane*16;
  short8 a = *(const short8*)g;
  short8 b = *(const short8*)(g + 8);
  float ss = 0.f;
  #pragma unroll
  for (int k=0;k<8;k++){
    float va = b2f_raw(a[k]), vb = b2f_raw(b[k]);
    ss += va*va + vb*vb;
  }
  #pragma unroll
  for (int o=1;o<64;o<<=1) ss += __shfl_xor(ss, o);
  if (lane == 0) srow[row] = rsqrtf(ss / DI + 1e-5f);
}

// ---------------------------------------------------------------------------
// wg[z][o][i] = out_w[z][o][i] * rms_w[z][i]  (row-scale commutation)
// ---------------------------------------------------------------------------
__global__ __launch_bounds__(256) void wg_scale(const bf16* __restrict__ w0,
    const bf16* __restrict__ w1, const bf16* __restrict__ r0,
    const bf16* __restrict__ r1, bf16* __restrict__ wg)
{
  int i = blockIdx.x*256 + threadIdx.x;   // 0..2*DM*DI-1
  int z = i >= DM*DI; int rem = z ? i - DM*DI : i;
  int col = rem & (DI-1);
  const bf16* w = z ? w1 : w0; const bf16* r = z ? r1 : r0;
  wg[i] = __float2bfloat16(__bfloat162float(w[rem]) * __bfloat162float(r[col]));
}

// ---------------------------------------------------------------------------
// Final LN over concat(h_f[b,t], h_b[b,T-1-t]) (1024) -> d_out
// ---------------------------------------------------------------------------
__global__ __launch_bounds__(256) void final_ln(const bf16* __restrict__ h,
    const bf16* __restrict__ lw, const bf16* __restrict__ lb, void* out,
    int mode, const int* flagp)
{
  __shared__ float sb[8];
  int bt = blockIdx.x; int b = bt >> 11, t = bt & 2047;
  int f32out = mode ? *flagp : 0;
  const bf16* rf = h + (long)bt*DM;
  const bf16* rb = h + ((long)BT + (long)b*TT + (TT-1-t))*DM;
  float v[4], s = 0.f, ss = 0.f;
  #pragma unroll
  for (int i=0;i<4;i++){
    int c = threadIdx.x + i*256;
    v[i] = __bfloat162float(c < DM ? rf[c] : rb[c-DM]);
    s += v[i]; ss += v[i]*v[i];
  }
  red2(s, ss, sb);
  float m = s / (2*DM);
  float var = ss / (2*DM) - m*m;
  float rs = rsqrtf(fmaxf(var, 0.f) + 1e-5f);
  #pragma unroll
  for (int i=0;i<4;i++){
    int c = threadIdx.x + i*256;
    float o = (v[i]-m)*rs*__bfloat162float(lw[c]) + __bfloat162float(lb[c]);
    if (f32out) ((float*)out)[(long)bt*(2*DM) + c] = o;
    else        ((bf16*)out)[(long)bt*(2*DM) + c] = __float2bfloat16(o);
  }
}

// ---------------------------------------------------------------------------
extern "C" void kernel_launch(void* const* d_in, const int* in_sizes, int n_in,
                              void* d_out, int out_size, void* d_ws, size_t ws_size,
                              hipStream_t stream)
{
  char* wsp = (char*)d_ws;
  auto take = [&](size_t bytes){ char* p = wsp; wsp += (bytes + 63) & ~(size_t)63; return p; };
  int*   flagp = (int*)  take(4);
  bf16*  h     = (bf16*) take((size_t)2*BT*DM*2);      // 16.78 MB
  bf16*  zx    = (bf16*) take((size_t)2*BT*DPROJ*2);   // 68.42 MB (gated in place)
  bf16*  xbc   = (bf16*) take((size_t)2*BT*CONVD*2);   // 34.60 MB
  float2* dadt = (float2*)take((size_t)2*BB*NH*TT*8);  // 1.05 MB
  float* srowb = (float*)take((size_t)2*BT*4);         // 64 KB
  float* Pc    = (float*)take((size_t)64*NCH*4);       // 4 KB
  float* SC    = (float*)take((size_t)NCH*NE*4);       // 8.39 MB chunk states
  bf16*  wg    = (bf16*)SC;   // overlays SC: live only after chunk_apply
  size_t needDirect = (size_t)(wsp - (char*)d_ws);     // ~129.3 MB (proven safe)

  static const int cnt[23] = {
    BT*256, DM*256, DM, DM, DM, 2*DM, 2*DM,
    NL*DPROJ*DM, NL*CONVD*4, NL*CONVD, NL*NH, NL*NH, NL*NH, NL*DI, NL*DM*DI,
    NL*DPROJ*DM, NL*CONVD*4, NL*CONVD, NL*NH, NL*NH, NL*NH, NL*DI, NL*DM*DI };
  bf16* canon[23];
  for (int i = 0; i < 23; ++i) canon[i] = (bf16*)take((size_t)cnt[i]*2);
  size_t needFull = (size_t)(wsp - (char*)d_ws);

  const int convMode = (ws_size >= needFull) ? 1 : 0;

  const bf16* in[23];
  if (convMode){
    detect_dtype<<<1,256,0,stream>>>(d_in[0], flagp);
    for (int i = 0; i < 23; ++i){
      int grid = (cnt[i] + 255)/256; if (grid > 2048) grid = 2048;
      convert_in<<<grid,256,0,stream>>>(d_in[i], canon[i], cnt[i], flagp);
      in[i] = canon[i];
    }
  } else {
    for (int i = 0; i < 23; ++i) in[i] = (const bf16*)d_in[i];
  }

  const bf16* x       = in[0];
  const bf16* embed_w = in[1];
  const bf16* embed_b = in[2];
  const bf16* ln1_w   = in[3];
  const bf16* ln1_b   = in[4];
  const bf16* lnout_w = in[5];
  const bf16* lnout_b = in[6];
  const bf16* in_w[2]   = {in[7],  in[15]};
  const bf16* conv_w[2] = {in[8],  in[16]};
  const bf16* conv_b[2] = {in[9],  in[17]};
  const bf16* dt_b[2]   = {in[10], in[18]};
  const bf16* A_log[2]  = {in[11], in[19]};
  const bf16* Dp[2]     = {in[12], in[20]};
  const bf16* rms_w[2]  = {in[13], in[21]};
  const bf16* out_w[2]  = {in[14], in[22]};

  bf16* hpre = xbc;   // embed output parks in xbc (free until layer-0 conv)

  gemm_nt<1><<<dim3(64,4,1),256,0,stream>>>(x, embed_w, embed_w, hpre, embed_b,
      nullptr, nullptr, nullptr, nullptr, nullptr, nullptr,
      BT, DM, 256, 256, 0, 0);
  embed_ln<<<dim3(BT),256,0,stream>>>(hpre, ln1_w, ln1_b, h);

  for (int i = 0; i < NL; ++i){
    gemm_nt<3><<<dim3(64,17,2),256,0,stream>>>(h,
        in_w[0]+(size_t)i*DPROJ*DM, in_w[1]+(size_t)i*DPROJ*DM,
        zx, nullptr, nullptr,
        dt_b[0]+i*NH, dt_b[1]+i*NH, A_log[0]+i*NH, A_log[1]+i*NH, dadt,
        BT, DPROJ, DM, DM, (long)BT*DM, (long)BT*DPROJ);
    conv_silu<<<dim3(BT,2),256,0,stream>>>(zx,
        conv_w[0]+(size_t)i*CONVD*4, conv_w[1]+(size_t)i*CONVD*4,
        conv_b[0]+(size_t)i*CONVD, conv_b[1]+(size_t)i*CONVD, xbc);
    chunk_local<<<dim3(NCH,32),256,0,stream>>>(xbc, dadt, SC, Pc);
    chunk_combine<<<dim3(NE/256),256,0,stream>>>(SC, Pc);
    chunk_apply<<<dim3(NCH,32),256,0,stream>>>(xbc, zx, dadt, SC,
        Dp[0]+i*NH, Dp[1]+i*NH);
    row_scale<<<dim3(2*BT/4),256,0,stream>>>(zx, srowb);
    wg_scale<<<dim3(2*DM*DI/256),256,0,stream>>>(out_w[0]+(size_t)i*DM*DI,
        out_w[1]+(size_t)i*DM*DI, rms_w[0]+(size_t)i*DI, rms_w[1]+(size_t)i*DI, wg);
    gemm_nt<4><<<dim3(64,4,2),256,0,stream>>>(zx, wg, wg+(size_t)DM*DI,
        h, h, srowb, nullptr, nullptr, nullptr, nullptr, nullptr,
        BT, DM, DI, DPROJ, (long)BT*DPROJ, (long)BT*DM);
  }

  final_ln<<<dim3(BT),256,0,stream>>>(h, lnout_w, lnout_b, d_out, convMode, flagp);
  (void)needDirect; (void)in_sizes; (void)n_in; (void)out_size;
}